// Round 1
// baseline (1612.142 us; speedup 1.0000x reference)
//
#include <hip/hip_runtime.h>

#define N_NODES 50000
#define N_EDGES 800000
// D_IN = D_HID = 128, D_OUT = 2

// ---------------- workspace layout (bytes, 256-aligned) ----------------
// cnt   [50000]  f32 @ 0            (200000 B)
// aggx  [50000*128] f32 @ 200192    (25.6 MB)
// h     [50000*128] f32 @ 25800192  (25.6 MB)
// y     [50000*2] f32 @ 51400192
// z     [50000*2] f32 @ 51800192
// aggy  [50000*2] f32 @ 52200192
// WlT   [128*128] f32 @ 52600192
// WrT   [128*128] f32 @ 52665728
// total ~52.8 MB

__global__ void transpose_w_kernel(const float* __restrict__ W1l,
                                   const float* __restrict__ W1r,
                                   float* __restrict__ WlT,
                                   float* __restrict__ WrT) {
    int t = blockIdx.x * 256 + threadIdx.x;   // 0 .. 32767
    int m = t >> 14;                          // 0: Wl, 1: Wr
    int u = t & 16383;
    int k = u >> 7, j = u & 127;
    if (m == 0) WlT[u] = W1l[j * 128 + k];
    else        WrT[u] = W1r[j * 128 + k];
}

__global__ void count_kernel(const int* __restrict__ dst, float* __restrict__ cnt) {
    int t = blockIdx.x * 256 + threadIdx.x;   // exactly 800000
    atomicAdd(&cnt[dst[t]], 1.0f);
}

// one thread per (edge, float4-chunk): gather x[src] row chunk, scatter-add to aggx[dst]
__global__ void scatter_x_kernel(const int* __restrict__ src, const int* __restrict__ dst,
                                 const float* __restrict__ x, float* __restrict__ aggx) {
    int t = blockIdx.x * 256 + threadIdx.x;   // exactly E*32 = 25,600,000
    int e = t >> 5, c4 = t & 31;
    int s = src[e], d = dst[e];
    float4 v = ((const float4*)x)[s * 32 + c4];
    float* p = aggx + d * 128 + c4 * 4;
    atomicAdd(p + 0, v.x);
    atomicAdd(p + 1, v.y);
    atomicAdd(p + 2, v.z);
    atomicAdd(p + 3, v.w);
}

// h = relu( (aggx/cnt) @ W1_l.T + x @ W1_r.T + b1 )
// block 256, tile 64 rows x 128 cols, 8x4 register tile per thread.
// WlT/WrT are [k][j] so B-reads are coalesced float4 across the wave.
__global__ __launch_bounds__(256) void gemm1_kernel(
    const float* __restrict__ x, const float* __restrict__ aggx,
    const float* __restrict__ cnt, const float* __restrict__ WlT,
    const float* __restrict__ WrT, const float* __restrict__ b1,
    float* __restrict__ h)
{
    __shared__ float As[64 * 128];   // x rows
    __shared__ float Ag[64 * 128];   // aggx rows pre-scaled by 1/max(cnt,1)
    const int i0 = blockIdx.x * 64;
    const int tid = threadIdx.x;

    #pragma unroll
    for (int s = 0; s < 8; ++s) {
        int v = tid + s * 256;        // float4 index 0..2047
        int row = v >> 5, c4 = v & 31;
        int gi = i0 + row;
        float4 xs = make_float4(0.f, 0.f, 0.f, 0.f), ga = xs;
        if (gi < N_NODES) {
            xs = ((const float4*)x)[gi * 32 + c4];
            ga = ((const float4*)aggx)[gi * 32 + c4];
            float inv = 1.0f / fmaxf(cnt[gi], 1.0f);
            ga.x *= inv; ga.y *= inv; ga.z *= inv; ga.w *= inv;
        }
        ((float4*)As)[v] = xs;
        ((float4*)Ag)[v] = ga;
    }
    __syncthreads();

    const int jt = tid & 31, it = tid >> 5;
    const int j0 = jt * 4, r0 = it * 8;
    float acc[8][4] = {};

    for (int kk4 = 0; kk4 < 32; ++kk4) {
        float a[8][4], g[8][4];
        #pragma unroll
        for (int r = 0; r < 8; ++r) {
            float4 t4 = ((const float4*)As)[(r0 + r) * 32 + kk4];
            a[r][0] = t4.x; a[r][1] = t4.y; a[r][2] = t4.z; a[r][3] = t4.w;
            float4 t5 = ((const float4*)Ag)[(r0 + r) * 32 + kk4];
            g[r][0] = t5.x; g[r][1] = t5.y; g[r][2] = t5.z; g[r][3] = t5.w;
        }
        #pragma unroll
        for (int q = 0; q < 4; ++q) {
            int k = kk4 * 4 + q;
            float4 wl = ((const float4*)WlT)[k * 32 + jt];
            float4 wr = ((const float4*)WrT)[k * 32 + jt];
            #pragma unroll
            for (int r = 0; r < 8; ++r) {
                acc[r][0] += g[r][q] * wl.x + a[r][q] * wr.x;
                acc[r][1] += g[r][q] * wl.y + a[r][q] * wr.y;
                acc[r][2] += g[r][q] * wl.z + a[r][q] * wr.z;
                acc[r][3] += g[r][q] * wl.w + a[r][q] * wr.w;
            }
        }
    }

    float4 bv = ((const float4*)b1)[jt];
    #pragma unroll
    for (int r = 0; r < 8; ++r) {
        int gi = i0 + r0 + r;
        if (gi < N_NODES) {
            float4 o;
            o.x = fmaxf(acc[r][0] + bv.x, 0.f);
            o.y = fmaxf(acc[r][1] + bv.y, 0.f);
            o.z = fmaxf(acc[r][2] + bv.z, 0.f);
            o.w = fmaxf(acc[r][3] + bv.w, 0.f);
            ((float4*)h)[gi * 32 + jt] = o;
        }
    }
}

// y = h @ W2_l.T, z = h @ W2_r.T  (each [N,2]); 16 lanes per node, shuffle-reduce
__global__ __launch_bounds__(256) void gemm2_kernel(
    const float* __restrict__ h, const float* __restrict__ W2l,
    const float* __restrict__ W2r, float* __restrict__ y, float* __restrict__ z)
{
    int lane = threadIdx.x & 63;
    int wave = threadIdx.x >> 6;
    int sub  = lane >> 4;
    int kl   = (lane & 15) * 8;
    int i = blockIdx.x * 16 + wave * 4 + sub;
    float a0 = 0.f, a1 = 0.f, a2 = 0.f, a3 = 0.f;
    if (i < N_NODES) {
        const float4* hp = (const float4*)(h + i * 128 + kl);
        float4 h0 = hp[0], h1 = hp[1];
        const float4* wl0 = (const float4*)(W2l + kl);
        const float4* wl1 = (const float4*)(W2l + 128 + kl);
        const float4* wr0 = (const float4*)(W2r + kl);
        const float4* wr1 = (const float4*)(W2r + 128 + kl);
        float4 p;
        p = wl0[0]; a0 += h0.x*p.x + h0.y*p.y + h0.z*p.z + h0.w*p.w;
        p = wl0[1]; a0 += h1.x*p.x + h1.y*p.y + h1.z*p.z + h1.w*p.w;
        p = wl1[0]; a1 += h0.x*p.x + h0.y*p.y + h0.z*p.z + h0.w*p.w;
        p = wl1[1]; a1 += h1.x*p.x + h1.y*p.y + h1.z*p.z + h1.w*p.w;
        p = wr0[0]; a2 += h0.x*p.x + h0.y*p.y + h0.z*p.z + h0.w*p.w;
        p = wr0[1]; a2 += h1.x*p.x + h1.y*p.y + h1.z*p.z + h1.w*p.w;
        p = wr1[0]; a3 += h0.x*p.x + h0.y*p.y + h0.z*p.z + h0.w*p.w;
        p = wr1[1]; a3 += h1.x*p.x + h1.y*p.y + h1.z*p.z + h1.w*p.w;
    }
    #pragma unroll
    for (int off = 1; off < 16; off <<= 1) {
        a0 += __shfl_xor(a0, off);
        a1 += __shfl_xor(a1, off);
        a2 += __shfl_xor(a2, off);
        a3 += __shfl_xor(a3, off);
    }
    if ((lane & 15) == 0 && i < N_NODES) {
        y[2 * i]     = a0;
        y[2 * i + 1] = a1;
        z[2 * i]     = a2;
        z[2 * i + 1] = a3;
    }
}

__global__ void scatter_y_kernel(const int* __restrict__ src, const int* __restrict__ dst,
                                 const float* __restrict__ y, float* __restrict__ aggy) {
    int t = blockIdx.x * 256 + threadIdx.x;   // exactly E*2 = 1,600,000
    int e = t >> 1, c = t & 1;
    atomicAdd(&aggy[dst[e] * 2 + c], y[src[e] * 2 + c]);
}

__global__ void final_kernel(const float* __restrict__ aggy, const float* __restrict__ z,
                             const float* __restrict__ cnt, const float* __restrict__ b2,
                             float* __restrict__ out) {
    int t = blockIdx.x * 256 + threadIdx.x;
    if (t < 2 * N_NODES) {
        int i = t >> 1, c = t & 1;
        out[t] = aggy[t] / fmaxf(cnt[i], 1.0f) + z[t] + b2[c];
    }
}

extern "C" void kernel_launch(void* const* d_in, const int* in_sizes, int n_in,
                              void* d_out, int out_size, void* d_ws, size_t ws_size,
                              hipStream_t stream) {
    const float* x   = (const float*)d_in[0];
    const int*   ei  = (const int*)  d_in[1];
    const float* W1l = (const float*)d_in[2];
    const float* W1r = (const float*)d_in[3];
    const float* b1  = (const float*)d_in[4];
    const float* W2l = (const float*)d_in[5];
    const float* W2r = (const float*)d_in[6];
    const float* b2  = (const float*)d_in[7];
    float* out = (float*)d_out;
    const int* src = ei;
    const int* dst = ei + N_EDGES;

    char* ws = (char*)d_ws;
    float* cnt  = (float*)(ws + 0);
    float* aggx = (float*)(ws + 200192);
    float* h    = (float*)(ws + 25800192);
    float* y    = (float*)(ws + 51400192);
    float* z    = (float*)(ws + 51800192);
    float* aggy = (float*)(ws + 52200192);
    float* WlT  = (float*)(ws + 52600192);
    float* WrT  = (float*)(ws + 52665728);

    hipMemsetAsync(cnt,  0, 200000,   stream);
    hipMemsetAsync(aggx, 0, 25600000, stream);
    hipMemsetAsync(aggy, 0, 400000,   stream);

    transpose_w_kernel<<<128, 256, 0, stream>>>(W1l, W1r, WlT, WrT);
    count_kernel<<<3125, 256, 0, stream>>>(dst, cnt);
    scatter_x_kernel<<<100000, 256, 0, stream>>>(src, dst, x, aggx);
    gemm1_kernel<<<782, 256, 0, stream>>>(x, aggx, cnt, WlT, WrT, b1, h);
    gemm2_kernel<<<3126, 256, 0, stream>>>(h, W2l, W2r, y, z);
    scatter_y_kernel<<<6250, 256, 0, stream>>>(src, dst, y, aggy);
    final_kernel<<<391, 256, 0, stream>>>(aggy, z, cnt, b2, out);
}

// Round 2
// 323.652 us; speedup vs baseline: 4.9811x; 4.9811x over previous
//
#include <hip/hip_runtime.h>

#define N_NODES 50000
#define N_EDGES 800000
// D_IN = D_HID = 128, D_OUT = 2

// ---------------- workspace layout (bytes, 256-aligned) ----------------
// deg    int[50000]      @ 0
// rowptr int[50000]      @ 200192
// cur    int[50000]      @ 400384
// bsum   int[256]        @ 600576
// csr    int[800000]     @ 601600
// aggx   f32[50000*128]  @ 3801600
// h      f32[50000*128]  @ 29401600
// y      f32[50000*2]    @ 55001600
// z      f32[50000*2]    @ 55401600
// WlT    f32[128*128]    @ 55801600
// WrT    f32[128*128]    @ 55867136   (total ~55.9 MB)

__global__ void transpose_w_kernel(const float* __restrict__ W1l,
                                   const float* __restrict__ W1r,
                                   float* __restrict__ WlT,
                                   float* __restrict__ WrT) {
    int t = blockIdx.x * 256 + threadIdx.x;   // 0 .. 32767
    int m = t >> 14;
    int u = t & 16383;
    int k = u >> 7, j = u & 127;
    if (m == 0) WlT[u] = W1l[j * 128 + k];
    else        WrT[u] = W1r[j * 128 + k];
}

__global__ void deg_kernel(const int* __restrict__ dst, int* __restrict__ deg) {
    int e = blockIdx.x * 256 + threadIdx.x;   // exactly 800000
    atomicAdd(&deg[dst[e]], 1);
}

// per-block exclusive scan of deg -> rowptr (partial), block totals -> bsum
__global__ void scan_block_kernel(const int* __restrict__ deg, int* __restrict__ rowptr,
                                  int* __restrict__ bsum) {
    __shared__ int s[256];
    int i = blockIdx.x * 256 + threadIdx.x;
    int v = (i < N_NODES) ? deg[i] : 0;
    s[threadIdx.x] = v;
    __syncthreads();
    #pragma unroll
    for (int off = 1; off < 256; off <<= 1) {
        int t = (threadIdx.x >= off) ? s[threadIdx.x - off] : 0;
        __syncthreads();
        s[threadIdx.x] += t;
        __syncthreads();
    }
    if (i < N_NODES) rowptr[i] = s[threadIdx.x] - v;   // exclusive within block
    if (threadIdx.x == 255) bsum[blockIdx.x] = s[255];
}

// scan the 196 block sums in place (bsum -> exclusive offsets)
__global__ void scan_bsum_kernel(int* __restrict__ bsum) {
    __shared__ int s[256];
    int v = (threadIdx.x < 196) ? bsum[threadIdx.x] : 0;
    s[threadIdx.x] = v;
    __syncthreads();
    #pragma unroll
    for (int off = 1; off < 256; off <<= 1) {
        int t = (threadIdx.x >= off) ? s[threadIdx.x - off] : 0;
        __syncthreads();
        s[threadIdx.x] += t;
        __syncthreads();
    }
    if (threadIdx.x < 196) bsum[threadIdx.x] = s[threadIdx.x] - v;
}

__global__ void add_off_kernel(int* __restrict__ rowptr, const int* __restrict__ bsum) {
    int i = blockIdx.x * 256 + threadIdx.x;
    if (i < N_NODES) rowptr[i] += bsum[blockIdx.x];
}

__global__ void fill_csr_kernel(const int* __restrict__ src, const int* __restrict__ dst,
                                const int* __restrict__ rowptr, int* __restrict__ cur,
                                int* __restrict__ csr) {
    int e = blockIdx.x * 256 + threadIdx.x;   // exactly 800000
    int d = dst[e];
    int pos = atomicAdd(&cur[d], 1);
    csr[rowptr[d] + pos] = src[e];
}

// pull-based aggregation: thread t -> (node, float4 chunk); no atomics.
__global__ __launch_bounds__(256) void agg_x_kernel(
    const int* __restrict__ rowptr, const int* __restrict__ deg,
    const int* __restrict__ csr, const float* __restrict__ x,
    float* __restrict__ aggx)
{
    int t = blockIdx.x * 256 + threadIdx.x;   // exactly 50000*32
    int node = t >> 5, c4 = t & 31;
    int beg = rowptr[node], n = deg[node];
    float4 acc = make_float4(0.f, 0.f, 0.f, 0.f);
    for (int j = 0; j < n; ++j) {
        int s = csr[beg + j];
        float4 v = ((const float4*)x)[s * 32 + c4];
        acc.x += v.x; acc.y += v.y; acc.z += v.z; acc.w += v.w;
    }
    ((float4*)aggx)[t] = acc;
}

// h = relu( (aggx/deg) @ W1_l.T + x @ W1_r.T + b1 )
__global__ __launch_bounds__(256) void gemm1_kernel(
    const float* __restrict__ x, const float* __restrict__ aggx,
    const int* __restrict__ deg, const float* __restrict__ WlT,
    const float* __restrict__ WrT, const float* __restrict__ b1,
    float* __restrict__ h)
{
    __shared__ float As[64 * 128];   // x rows
    __shared__ float Ag[64 * 128];   // aggx rows pre-scaled by 1/max(deg,1)
    const int i0 = blockIdx.x * 64;
    const int tid = threadIdx.x;

    #pragma unroll
    for (int s = 0; s < 8; ++s) {
        int v = tid + s * 256;        // float4 index 0..2047
        int row = v >> 5, c4 = v & 31;
        int gi = i0 + row;
        float4 xs = make_float4(0.f, 0.f, 0.f, 0.f), ga = xs;
        if (gi < N_NODES) {
            xs = ((const float4*)x)[gi * 32 + c4];
            ga = ((const float4*)aggx)[gi * 32 + c4];
            float inv = 1.0f / fmaxf((float)deg[gi], 1.0f);
            ga.x *= inv; ga.y *= inv; ga.z *= inv; ga.w *= inv;
        }
        ((float4*)As)[v] = xs;
        ((float4*)Ag)[v] = ga;
    }
    __syncthreads();

    const int jt = tid & 31, it = tid >> 5;
    const int r0 = it * 8;
    float acc[8][4] = {};

    for (int kk4 = 0; kk4 < 32; ++kk4) {
        float a[8][4], g[8][4];
        #pragma unroll
        for (int r = 0; r < 8; ++r) {
            float4 t4 = ((const float4*)As)[(r0 + r) * 32 + kk4];
            a[r][0] = t4.x; a[r][1] = t4.y; a[r][2] = t4.z; a[r][3] = t4.w;
            float4 t5 = ((const float4*)Ag)[(r0 + r) * 32 + kk4];
            g[r][0] = t5.x; g[r][1] = t5.y; g[r][2] = t5.z; g[r][3] = t5.w;
        }
        #pragma unroll
        for (int q = 0; q < 4; ++q) {
            int k = kk4 * 4 + q;
            float4 wl = ((const float4*)WlT)[k * 32 + jt];
            float4 wr = ((const float4*)WrT)[k * 32 + jt];
            #pragma unroll
            for (int r = 0; r < 8; ++r) {
                acc[r][0] += g[r][q] * wl.x + a[r][q] * wr.x;
                acc[r][1] += g[r][q] * wl.y + a[r][q] * wr.y;
                acc[r][2] += g[r][q] * wl.z + a[r][q] * wr.z;
                acc[r][3] += g[r][q] * wl.w + a[r][q] * wr.w;
            }
        }
    }

    float4 bv = ((const float4*)b1)[jt];
    #pragma unroll
    for (int r = 0; r < 8; ++r) {
        int gi = i0 + r0 + r;
        if (gi < N_NODES) {
            float4 o;
            o.x = fmaxf(acc[r][0] + bv.x, 0.f);
            o.y = fmaxf(acc[r][1] + bv.y, 0.f);
            o.z = fmaxf(acc[r][2] + bv.z, 0.f);
            o.w = fmaxf(acc[r][3] + bv.w, 0.f);
            ((float4*)h)[gi * 32 + jt] = o;
        }
    }
}

// y = h @ W2_l.T, z = h @ W2_r.T  (each [N,2]); 16 lanes per node, shuffle-reduce
__global__ __launch_bounds__(256) void gemm2_kernel(
    const float* __restrict__ h, const float* __restrict__ W2l,
    const float* __restrict__ W2r, float* __restrict__ y, float* __restrict__ z)
{
    int lane = threadIdx.x & 63;
    int wave = threadIdx.x >> 6;
    int sub  = lane >> 4;
    int kl   = (lane & 15) * 8;
    int i = blockIdx.x * 16 + wave * 4 + sub;
    float a0 = 0.f, a1 = 0.f, a2 = 0.f, a3 = 0.f;
    if (i < N_NODES) {
        const float4* hp = (const float4*)(h + i * 128 + kl);
        float4 h0 = hp[0], h1 = hp[1];
        const float4* wl0 = (const float4*)(W2l + kl);
        const float4* wl1 = (const float4*)(W2l + 128 + kl);
        const float4* wr0 = (const float4*)(W2r + kl);
        const float4* wr1 = (const float4*)(W2r + 128 + kl);
        float4 p;
        p = wl0[0]; a0 += h0.x*p.x + h0.y*p.y + h0.z*p.z + h0.w*p.w;
        p = wl0[1]; a0 += h1.x*p.x + h1.y*p.y + h1.z*p.z + h1.w*p.w;
        p = wl1[0]; a1 += h0.x*p.x + h0.y*p.y + h0.z*p.z + h0.w*p.w;
        p = wl1[1]; a1 += h1.x*p.x + h1.y*p.y + h1.z*p.z + h1.w*p.w;
        p = wr0[0]; a2 += h0.x*p.x + h0.y*p.y + h0.z*p.z + h0.w*p.w;
        p = wr0[1]; a2 += h1.x*p.x + h1.y*p.y + h1.z*p.z + h1.w*p.w;
        p = wr1[0]; a3 += h0.x*p.x + h0.y*p.y + h0.z*p.z + h0.w*p.w;
        p = wr1[1]; a3 += h1.x*p.x + h1.y*p.y + h1.z*p.z + h1.w*p.w;
    }
    #pragma unroll
    for (int off = 1; off < 16; off <<= 1) {
        a0 += __shfl_xor(a0, off);
        a1 += __shfl_xor(a1, off);
        a2 += __shfl_xor(a2, off);
        a3 += __shfl_xor(a3, off);
    }
    if ((lane & 15) == 0 && i < N_NODES) {
        y[2 * i]     = a0;
        y[2 * i + 1] = a1;
        z[2 * i]     = a2;
        z[2 * i + 1] = a3;
    }
}

// out = csr-mean(y) + z + b2 ; pull-based, no atomics
__global__ void final_kernel(const int* __restrict__ rowptr, const int* __restrict__ deg,
                             const int* __restrict__ csr, const float* __restrict__ y,
                             const float* __restrict__ z, const float* __restrict__ b2,
                             float* __restrict__ out) {
    int t = blockIdx.x * 256 + threadIdx.x;
    if (t >= 2 * N_NODES) return;
    int node = t >> 1, c = t & 1;
    int beg = rowptr[node], n = deg[node];
    float acc = 0.f;
    for (int j = 0; j < n; ++j) acc += y[csr[beg + j] * 2 + c];
    out[t] = acc / fmaxf((float)n, 1.0f) + z[t] + b2[c];
}

extern "C" void kernel_launch(void* const* d_in, const int* in_sizes, int n_in,
                              void* d_out, int out_size, void* d_ws, size_t ws_size,
                              hipStream_t stream) {
    const float* x   = (const float*)d_in[0];
    const int*   ei  = (const int*)  d_in[1];
    const float* W1l = (const float*)d_in[2];
    const float* W1r = (const float*)d_in[3];
    const float* b1  = (const float*)d_in[4];
    const float* W2l = (const float*)d_in[5];
    const float* W2r = (const float*)d_in[6];
    const float* b2  = (const float*)d_in[7];
    float* out = (float*)d_out;
    const int* src = ei;
    const int* dst = ei + N_EDGES;

    char* ws = (char*)d_ws;
    int*   deg    = (int*)  (ws + 0);
    int*   rowptr = (int*)  (ws + 200192);
    int*   cur    = (int*)  (ws + 400384);
    int*   bsum   = (int*)  (ws + 600576);
    int*   csr    = (int*)  (ws + 601600);
    float* aggx   = (float*)(ws + 3801600);
    float* h      = (float*)(ws + 29401600);
    float* y      = (float*)(ws + 55001600);
    float* z      = (float*)(ws + 55401600);
    float* WlT    = (float*)(ws + 55801600);
    float* WrT    = (float*)(ws + 55867136);

    hipMemsetAsync(deg, 0, 200000, stream);
    hipMemsetAsync(cur, 0, 200000, stream);

    transpose_w_kernel<<<128, 256, 0, stream>>>(W1l, W1r, WlT, WrT);
    deg_kernel<<<3125, 256, 0, stream>>>(dst, deg);
    scan_block_kernel<<<196, 256, 0, stream>>>(deg, rowptr, bsum);
    scan_bsum_kernel<<<1, 256, 0, stream>>>(bsum);
    add_off_kernel<<<196, 256, 0, stream>>>(rowptr, bsum);
    fill_csr_kernel<<<3125, 256, 0, stream>>>(src, dst, rowptr, cur, csr);
    agg_x_kernel<<<6250, 256, 0, stream>>>(rowptr, deg, csr, x, aggx);
    gemm1_kernel<<<782, 256, 0, stream>>>(x, aggx, deg, WlT, WrT, b1, h);
    gemm2_kernel<<<3126, 256, 0, stream>>>(h, W2l, W2r, y, z);
    final_kernel<<<391, 256, 0, stream>>>(rowptr, deg, csr, y, z, b2, out);
}

// Round 3
// 266.853 us; speedup vs baseline: 6.0413x; 1.2129x over previous
//
#include <hip/hip_runtime.h>

#define N_NODES 50000
#define N_EDGES 800000
// D_IN = D_HID = 128, D_OUT = 2

typedef __bf16 bf16_8 __attribute__((ext_vector_type(8)));
typedef float  f32_4  __attribute__((ext_vector_type(4)));

// ---------------- workspace layout (bytes, 256-aligned) ----------------
// deg    int[50000]        @ 0
// rowptr int[50000]        @ 200192
// cur    int[50000]        @ 400384
// bsum   int[256]          @ 600576
// csr    int[800000]       @ 601600
// Ab     bf16[50000*256]   @ 3801600   (cols 0-127: mean-agg, 128-255: x)
// h      bf16[50000*128]   @ 29401600
// y      f32[50000*2]      @ 42201600
// z      f32[50000*2]      @ 42601600
// Wt     bf16[128*256]     @ 43001600  (Wcat row-major: [n][k], k<128 = W1l, else W1r)
// total ~43.1 MB

__global__ void prep_w_kernel(const float* __restrict__ W1l,
                              const float* __restrict__ W1r,
                              __bf16* __restrict__ Wt) {
    int t = blockIdx.x * 256 + threadIdx.x;   // exactly 32768
    int n = t >> 8, k = t & 255;
    float v = (k < 128) ? W1l[n * 128 + k] : W1r[n * 128 + (k - 128)];
    Wt[t] = (__bf16)v;
}

// x -> bf16 into Ab cols 128..255
__global__ void conv_x_kernel(const float* __restrict__ x, __bf16* __restrict__ Ab) {
    int t = blockIdx.x * 256 + threadIdx.x;   // exactly 50000*16 = 800000
    int node = t >> 4, c8 = t & 15;
    const float4* xp = (const float4*)(x + node * 128 + c8 * 8);
    float4 v0 = xp[0], v1 = xp[1];
    bf16_8 o;
    o[0] = (__bf16)v0.x; o[1] = (__bf16)v0.y; o[2] = (__bf16)v0.z; o[3] = (__bf16)v0.w;
    o[4] = (__bf16)v1.x; o[5] = (__bf16)v1.y; o[6] = (__bf16)v1.z; o[7] = (__bf16)v1.w;
    *(bf16_8*)(Ab + node * 256 + 128 + c8 * 8) = o;
}

__global__ void deg_kernel(const int* __restrict__ dst, int* __restrict__ deg) {
    int e = blockIdx.x * 256 + threadIdx.x;   // exactly 800000
    atomicAdd(&deg[dst[e]], 1);
}

__global__ void scan_block_kernel(const int* __restrict__ deg, int* __restrict__ rowptr,
                                  int* __restrict__ bsum) {
    __shared__ int s[256];
    int i = blockIdx.x * 256 + threadIdx.x;
    int v = (i < N_NODES) ? deg[i] : 0;
    s[threadIdx.x] = v;
    __syncthreads();
    #pragma unroll
    for (int off = 1; off < 256; off <<= 1) {
        int t = (threadIdx.x >= off) ? s[threadIdx.x - off] : 0;
        __syncthreads();
        s[threadIdx.x] += t;
        __syncthreads();
    }
    if (i < N_NODES) rowptr[i] = s[threadIdx.x] - v;
    if (threadIdx.x == 255) bsum[blockIdx.x] = s[255];
}

__global__ void scan_bsum_kernel(int* __restrict__ bsum) {
    __shared__ int s[256];
    int v = (threadIdx.x < 196) ? bsum[threadIdx.x] : 0;
    s[threadIdx.x] = v;
    __syncthreads();
    #pragma unroll
    for (int off = 1; off < 256; off <<= 1) {
        int t = (threadIdx.x >= off) ? s[threadIdx.x - off] : 0;
        __syncthreads();
        s[threadIdx.x] += t;
        __syncthreads();
    }
    if (threadIdx.x < 196) bsum[threadIdx.x] = s[threadIdx.x] - v;
}

__global__ void add_off_kernel(int* __restrict__ rowptr, const int* __restrict__ bsum) {
    int i = blockIdx.x * 256 + threadIdx.x;
    if (i < N_NODES) rowptr[i] += bsum[blockIdx.x];
}

__global__ void fill_csr_kernel(const int* __restrict__ src, const int* __restrict__ dst,
                                const int* __restrict__ rowptr, int* __restrict__ cur,
                                int* __restrict__ csr) {
    int e = blockIdx.x * 256 + threadIdx.x;   // exactly 800000
    int d = dst[e];
    int pos = atomicAdd(&cur[d], 1);
    csr[rowptr[d] + pos] = src[e];
}

// pull-based mean-agg over bf16 x (Ab cols 128..255) -> Ab cols 0..127, fp32 accum
__global__ __launch_bounds__(256) void agg_kernel(
    const int* __restrict__ rowptr, const int* __restrict__ deg,
    const int* __restrict__ csr, __bf16* __restrict__ Ab)
{
    int t = blockIdx.x * 256 + threadIdx.x;   // exactly 50000*16 = 800000
    int node = t >> 4, c8 = t & 15;
    int beg = rowptr[node], n = deg[node];
    float acc[8] = {};
    for (int j = 0; j < n; ++j) {
        int s = csr[beg + j];
        bf16_8 v = *(const bf16_8*)(Ab + s * 256 + 128 + c8 * 8);
        #pragma unroll
        for (int u = 0; u < 8; ++u) acc[u] += (float)v[u];
    }
    float inv = 1.0f / fmaxf((float)n, 1.0f);
    bf16_8 o;
    #pragma unroll
    for (int u = 0; u < 8; ++u) o[u] = (__bf16)(acc[u] * inv);
    *(bf16_8*)(Ab + node * 256 + c8 * 8) = o;
}

// h = relu( Ab[50000x256] @ Wt^T + b1 ), bf16 MFMA 16x16x32, K=256.
// Block: 256 thr (4 waves), tile M=64 x N=128. Wave w: rows w*16..w*16+15, all 128 cols.
#define LDA 264   // padded LDS row (bf16 elements): 264*2=528B -> conflict-free b128 reads
__global__ __launch_bounds__(256) void gemm1_kernel(
    const __bf16* __restrict__ Ab, const __bf16* __restrict__ Wt,
    const float* __restrict__ b1, __bf16* __restrict__ h)
{
    __shared__ __bf16 As[64 * LDA];
    const int i0 = blockIdx.x * 64;
    const int tid = threadIdx.x;

    // stage 64x256 bf16 (32KB): 2048 16B-chunks, 8 per thread, coalesced
    #pragma unroll
    for (int s = 0; s < 8; ++s) {
        int v = tid + s * 256;
        int row = v >> 5, c8 = v & 31;
        int gi = i0 + row;
        bf16_8 val = {};
        if (gi < N_NODES) val = ((const bf16_8*)(Ab + gi * 256))[c8];
        *(bf16_8*)(&As[row * LDA + c8 * 8]) = val;
    }
    __syncthreads();

    const int wv = tid >> 6, lane = tid & 63;
    const int m0 = wv * 16;
    const int mr = lane & 15, q = lane >> 4;

    f32_4 acc[8];
    #pragma unroll
    for (int nt = 0; nt < 8; ++nt) acc[nt] = (f32_4){0.f, 0.f, 0.f, 0.f};

    #pragma unroll
    for (int ks = 0; ks < 8; ++ks) {            // k0 = ks*32
        bf16_8 a = *(const bf16_8*)(&As[(m0 + mr) * LDA + ks * 32 + q * 8]);
        #pragma unroll
        for (int nt = 0; nt < 8; ++nt) {
            bf16_8 b = *(const bf16_8*)(Wt + (nt * 16 + mr) * 256 + ks * 32 + q * 8);
            acc[nt] = __builtin_amdgcn_mfma_f32_16x16x32_bf16(a, b, acc[nt], 0, 0, 0);
        }
    }

    // C/D layout: col = lane&15, row = q*4 + reg  [m89-verified]
    #pragma unroll
    for (int nt = 0; nt < 8; ++nt) {
        int col = nt * 16 + mr;
        float bb = b1[col];
        #pragma unroll
        for (int r = 0; r < 4; ++r) {
            int row = i0 + m0 + q * 4 + r;
            if (row < N_NODES)
                h[row * 128 + col] = (__bf16)fmaxf(acc[nt][r] + bb, 0.f);
        }
    }
}

// y = h @ W2_l.T, z = h @ W2_r.T ; 16 lanes/node, shuffle-reduce. h is bf16.
__global__ __launch_bounds__(256) void gemm2_kernel(
    const __bf16* __restrict__ h, const float* __restrict__ W2l,
    const float* __restrict__ W2r, float* __restrict__ y, float* __restrict__ z)
{
    int lane = threadIdx.x & 63;
    int wave = threadIdx.x >> 6;
    int sub  = lane >> 4;
    int kl   = (lane & 15) * 8;
    int i = blockIdx.x * 16 + wave * 4 + sub;
    float a0 = 0.f, a1 = 0.f, a2 = 0.f, a3 = 0.f;
    if (i < N_NODES) {
        bf16_8 hb = *(const bf16_8*)(h + i * 128 + kl);
        float hv[8];
        #pragma unroll
        for (int u = 0; u < 8; ++u) hv[u] = (float)hb[u];
        const float4* wl0 = (const float4*)(W2l + kl);
        const float4* wl1 = (const float4*)(W2l + 128 + kl);
        const float4* wr0 = (const float4*)(W2r + kl);
        const float4* wr1 = (const float4*)(W2r + 128 + kl);
        float4 p;
        p = wl0[0]; a0 += hv[0]*p.x + hv[1]*p.y + hv[2]*p.z + hv[3]*p.w;
        p = wl0[1]; a0 += hv[4]*p.x + hv[5]*p.y + hv[6]*p.z + hv[7]*p.w;
        p = wl1[0]; a1 += hv[0]*p.x + hv[1]*p.y + hv[2]*p.z + hv[3]*p.w;
        p = wl1[1]; a1 += hv[4]*p.x + hv[5]*p.y + hv[6]*p.z + hv[7]*p.w;
        p = wr0[0]; a2 += hv[0]*p.x + hv[1]*p.y + hv[2]*p.z + hv[3]*p.w;
        p = wr0[1]; a2 += hv[4]*p.x + hv[5]*p.y + hv[6]*p.z + hv[7]*p.w;
        p = wr1[0]; a3 += hv[0]*p.x + hv[1]*p.y + hv[2]*p.z + hv[3]*p.w;
        p = wr1[1]; a3 += hv[4]*p.x + hv[5]*p.y + hv[6]*p.z + hv[7]*p.w;
    }
    #pragma unroll
    for (int off = 1; off < 16; off <<= 1) {
        a0 += __shfl_xor(a0, off);
        a1 += __shfl_xor(a1, off);
        a2 += __shfl_xor(a2, off);
        a3 += __shfl_xor(a3, off);
    }
    if ((lane & 15) == 0 && i < N_NODES) {
        y[2 * i]     = a0;
        y[2 * i + 1] = a1;
        z[2 * i]     = a2;
        z[2 * i + 1] = a3;
    }
}

// out = csr-mean(y) + z + b2 ; pull-based, no atomics
__global__ void final_kernel(const int* __restrict__ rowptr, const int* __restrict__ deg,
                             const int* __restrict__ csr, const float* __restrict__ y,
                             const float* __restrict__ z, const float* __restrict__ b2,
                             float* __restrict__ out) {
    int t = blockIdx.x * 256 + threadIdx.x;
    if (t >= 2 * N_NODES) return;
    int node = t >> 1, c = t & 1;
    int beg = rowptr[node], n = deg[node];
    float acc = 0.f;
    for (int j = 0; j < n; ++j) acc += y[csr[beg + j] * 2 + c];
    out[t] = acc / fmaxf((float)n, 1.0f) + z[t] + b2[c];
}

extern "C" void kernel_launch(void* const* d_in, const int* in_sizes, int n_in,
                              void* d_out, int out_size, void* d_ws, size_t ws_size,
                              hipStream_t stream) {
    const float* x   = (const float*)d_in[0];
    const int*   ei  = (const int*)  d_in[1];
    const float* W1l = (const float*)d_in[2];
    const float* W1r = (const float*)d_in[3];
    const float* b1  = (const float*)d_in[4];
    const float* W2l = (const float*)d_in[5];
    const float* W2r = (const float*)d_in[6];
    const float* b2  = (const float*)d_in[7];
    float* out = (float*)d_out;
    const int* src = ei;
    const int* dst = ei + N_EDGES;

    char* ws = (char*)d_ws;
    int*    deg    = (int*)   (ws + 0);
    int*    rowptr = (int*)   (ws + 200192);
    int*    cur    = (int*)   (ws + 400384);
    int*    bsum   = (int*)   (ws + 600576);
    int*    csr    = (int*)   (ws + 601600);
    __bf16* Ab     = (__bf16*)(ws + 3801600);
    __bf16* h      = (__bf16*)(ws + 29401600);
    float*  y      = (float*) (ws + 42201600);
    float*  z      = (float*) (ws + 42601600);
    __bf16* Wt     = (__bf16*)(ws + 43001600);

    hipMemsetAsync(deg, 0, 200000, stream);
    hipMemsetAsync(cur, 0, 200000, stream);

    prep_w_kernel<<<128, 256, 0, stream>>>(W1l, W1r, Wt);
    conv_x_kernel<<<3125, 256, 0, stream>>>(x, Ab);
    deg_kernel<<<3125, 256, 0, stream>>>(dst, deg);
    scan_block_kernel<<<196, 256, 0, stream>>>(deg, rowptr, bsum);
    scan_bsum_kernel<<<1, 256, 0, stream>>>(bsum);
    add_off_kernel<<<196, 256, 0, stream>>>(rowptr, bsum);
    fill_csr_kernel<<<3125, 256, 0, stream>>>(src, dst, rowptr, cur, csr);
    agg_kernel<<<3125, 256, 0, stream>>>(rowptr, deg, csr, Ab);
    gemm1_kernel<<<782, 256, 0, stream>>>(Ab, Wt, b1, h);
    gemm2_kernel<<<3126, 256, 0, stream>>>(h, W2l, W2r, y, z);
    final_kernel<<<391, 256, 0, stream>>>(rowptr, deg, csr, y, z, b2, out);
}